// Round 10
// baseline (16.365 us; speedup 1.0000x reference)
//
#include <hip/hip_runtime.h>

#define FEAT 2048
#define CH 16            // output rows per chunk
#define COLSPLIT 4
#define THREADS 128      // 128 threads * 4 floats = 512 = FEAT/COLSPLIT
#define NROWS_LD (CH + 4)

// total = sum_r sum_{delta=1..4} W(r,delta) * g(r, r+delta),
// g(r,s) = sum_feat relu(x_r - x_s), W(r,delta) = sum_{i=0}^{4-delta} cnt[r-i],
// cnt[v] = multiplicity of base value v = batch*distort (batch<64, distort<24).
struct Tables {
    int nchunk;
    short r0[1456];
    float W[1472][4];
};

constexpr Tables make_tables() {
    Tables t{};
    int cnt[1450] = {};
    for (int b = 0; b < 64; ++b)
        for (int d = 0; d < 24; ++d)
            cnt[b * d]++;
    for (int r = 0; r < 1472; ++r)
        for (int dl = 1; dl <= 4; ++dl) {
            int s = 0;
            for (int i = 0; i <= 4 - dl; ++i) {
                int v = r - i;
                if (v >= 0 && v < 1450) s += cnt[v];
            }
            t.W[r][dl - 1] = (float)s;
        }
    t.nchunk = 0;
    int r = 0;
    while (r < 1453) {
        bool act = false;
        for (int i = 0; i <= 3; ++i) {
            int v = r - i;
            if (v >= 0 && v < 1450 && cnt[v] > 0) act = true;
        }
        if (act) { t.r0[t.nchunk++] = (short)r; r += CH; }
        else ++r;
    }
    return t;
}

constexpr Tables TBL = make_tables();
constexpr int NCHUNK = TBL.nchunk;           // 93
constexpr int NBLK   = NCHUNK * COLSPLIT;    // 372 — spreads memory over all CUs
constexpr int NGRP   = 8;                    // 8 group counters, separate cache lines

__constant__ Tables d_tbl = make_tables();

// Hierarchical last-block-done (contention fix for R8's 25us same-line tail):
// blocks bump their group counter (8 lines in parallel, ~47 RMWs each);
// group-last blocks bump the final counter (8 RMWs). All counters are
// SELF-RESETTING and poison-aware (pattern validated R8/R9): detect
// prev == size-1 (steady: reset to 0 each run) or prev == 0xAAAAAAAA+size-1
// (first replay after the harness's one-time 0xAA ws-poison).
__global__ __launch_bounds__(THREADS) void hinge_fused(const float* __restrict__ in,
                                                       float* __restrict__ partial,
                                                       unsigned* __restrict__ counters,
                                                       float* __restrict__ out) {
    const int chunk = blockIdx.x >> 2;        // / COLSPLIT
    const int cpart = blockIdx.x & 3;         // % COLSPLIT
    const int r0    = d_tbl.r0[chunk];
    const float* p  = in + (long)r0 * FEAT + cpart * (FEAT / COLSPLIT) + threadIdx.x * 4;

    // All loads upfront — 20 independent dwordx4, one latency burst.
    float4 x[NROWS_LD];
    #pragma unroll
    for (int l = 0; l < NROWS_LD; ++l)
        x[l] = *(const float4*)(p + l * FEAT);

    float acc0 = 0.f, acc1 = 0.f;
    #pragma unroll
    for (int k = 0; k < CH; ++k) {
        #pragma unroll
        for (int dl = 1; dl <= 4; ++dl) {
            const float w = d_tbl.W[r0 + k][dl - 1];
            float s = fmaxf(x[k].x - x[k + dl].x, 0.f)
                    + fmaxf(x[k].y - x[k + dl].y, 0.f)
                    + fmaxf(x[k].z - x[k + dl].z, 0.f)
                    + fmaxf(x[k].w - x[k + dl].w, 0.f);
            if (dl & 1) acc0 = fmaf(w, s, acc0);
            else        acc1 = fmaf(w, s, acc1);
        }
    }

    float acc = acc0 + acc1;
    #pragma unroll
    for (int off = 32; off > 0; off >>= 1)
        acc += __shfl_down(acc, off, 64);

    __shared__ float ws[THREADS / 64];
    __shared__ int   lastf;
    const int lane = threadIdx.x & 63, wave = threadIdx.x >> 6;
    if (lane == 0) ws[wave] = acc;
    __syncthreads();

    if (threadIdx.x == 0) {
        partial[blockIdx.x] = ws[0] + ws[1];
        __threadfence();                               // release: partial visible
        const int gid   = blockIdx.x & (NGRP - 1);
        const unsigned gsize = (NBLK >> 3) + (gid < (NBLK & 7) ? 1u : 0u);
        unsigned* gcnt = counters + gid * 64;          // 256-B separation
        unsigned* fcnt = counters + NGRP * 64;
        int f = 0;
        unsigned gp = atomicAdd(gcnt, 1u);
        if (gp == gsize - 1u || gp == 0xAAAAAAAAu + gsize - 1u) {
            atomicExch(gcnt, 0u);                      // reset own group counter
            unsigned fp = atomicAdd(fcnt, 1u);
            if (fp == (unsigned)(NGRP - 1) ||
                fp == 0xAAAAAAAAu + (unsigned)(NGRP - 1)) {
                atomicExch(fcnt, 0u);                  // reset final counter
                f = 1;
            }
        }
        lastf = f;
    }
    __syncthreads();

    if (lastf) {
        __threadfence();                               // acquire: all partials visible
        float a = 0.f;
        constexpr int NV4 = NBLK / 4;                  // 93 float4
        for (int i = threadIdx.x; i < NV4; i += THREADS) {
            float4 v = ((const float4*)partial)[i];
            a += (v.x + v.y) + (v.z + v.w);
        }
        #pragma unroll
        for (int off = 32; off > 0; off >>= 1)
            a += __shfl_down(a, off, 64);
        if (lane == 0) ws[wave] = a;
        __syncthreads();
        if (threadIdx.x == 0) out[0] = ws[0] + ws[1];
    }
}

extern "C" void kernel_launch(void* const* d_in, const int* in_sizes, int n_in,
                              void* d_out, int out_size, void* d_ws, size_t ws_size,
                              hipStream_t stream) {
    const float* in    = (const float*)d_in[0];
    float* out         = (float*)d_out;
    float* partial     = (float*)d_ws;                      // NBLK floats
    unsigned* counters = (unsigned*)((char*)d_ws + 8192);   // 9 lines x 256 B

    hinge_fused<<<NBLK, THREADS, 0, stream>>>(in, partial, counters, out);
}

// Round 11
// 12.299 us; speedup vs baseline: 1.3306x; 1.3306x over previous
//
#include <hip/hip_runtime.h>

#define FEAT 2048
#define CH 8             // output rows per chunk
#define COLSPLIT 8
#define THREADS 64       // 64 threads * 4 floats = 256 = FEAT/COLSPLIT
#define NROWS_LD (CH + 4)

// total = sum_r sum_{delta=1..4} W(r,delta) * g(r, r+delta),
// g(r,s) = sum_feat relu(x_r - x_s), W(r,delta) = sum_{i=0}^{4-delta} cnt[r-i],
// cnt[v] = multiplicity of base value v = batch*distort (batch<64, distort<24).
//
// Structure note (R4-R10 measured): two plain dispatches is the FLOOR here.
// Single-dispatch alternatives all regress: +fill node = +10.5us, coop
// grid.sync = +46us, flat last-block counter @1456 blocks = +25us, @93
// blocks = +0.7us, hierarchical counters @372 = +5.4us. Device-scope
// fence/atomic completion detection costs more than a dispatch on MI355X.
struct Tables {
    int nchunk;
    short r0[1456];
    float W[1472][4];
};

constexpr Tables make_tables() {
    Tables t{};
    int cnt[1450] = {};
    for (int b = 0; b < 64; ++b)
        for (int d = 0; d < 24; ++d)
            cnt[b * d]++;
    for (int r = 0; r < 1472; ++r)
        for (int dl = 1; dl <= 4; ++dl) {
            int s = 0;
            for (int i = 0; i <= 4 - dl; ++i) {
                int v = r - i;
                if (v >= 0 && v < 1450) s += cnt[v];
            }
            t.W[r][dl - 1] = (float)s;
        }
    t.nchunk = 0;
    int r = 0;
    while (r < 1453) {
        bool act = false;
        for (int i = 0; i <= 3; ++i) {
            int v = r - i;
            if (v >= 0 && v < 1450 && cnt[v] > 0) act = true;
        }
        if (act) { t.r0[t.nchunk++] = (short)r; r += CH; }
        else ++r;
    }
    return t;
}

constexpr Tables TBL = make_tables();
constexpr int NCHUNK = TBL.nchunk;
constexpr int NPART  = NCHUNK * COLSPLIT;

__constant__ Tables d_tbl = make_tables();

__global__ __launch_bounds__(THREADS) void hinge_rows(const float* __restrict__ in,
                                                      float* __restrict__ partial) {
    const int chunk = blockIdx.x >> 3;        // / COLSPLIT
    const int cpart = blockIdx.x & 7;         // % COLSPLIT
    const int r0    = d_tbl.r0[chunk];
    const float* p  = in + (long)r0 * FEAT + cpart * (FEAT / COLSPLIT) + threadIdx.x * 4;

    // All loads upfront — independent, one latency burst.
    float4 x[NROWS_LD];
    #pragma unroll
    for (int l = 0; l < NROWS_LD; ++l)
        x[l] = *(const float4*)(p + l * FEAT);

    float acc0 = 0.f, acc1 = 0.f;
    #pragma unroll
    for (int k = 0; k < CH; ++k) {
        #pragma unroll
        for (int dl = 1; dl <= 4; ++dl) {
            const float w = d_tbl.W[r0 + k][dl - 1];
            float s = fmaxf(x[k].x - x[k + dl].x, 0.f)
                    + fmaxf(x[k].y - x[k + dl].y, 0.f)
                    + fmaxf(x[k].z - x[k + dl].z, 0.f)
                    + fmaxf(x[k].w - x[k + dl].w, 0.f);
            if (dl & 1) acc0 = fmaf(w, s, acc0);
            else        acc1 = fmaf(w, s, acc1);
        }
    }

    float acc = acc0 + acc1;
    #pragma unroll
    for (int off = 32; off > 0; off >>= 1)
        acc += __shfl_down(acc, off, 64);

    if (threadIdx.x == 0) partial[blockIdx.x] = acc;
}

// Single-wave final reduce: 64 threads, float4 loads, no LDS, no barriers.
__global__ __launch_bounds__(64) void reduce_final(const float* __restrict__ partial,
                                                   float* __restrict__ out) {
    const int t = threadIdx.x;
    constexpr int NV4 = NPART / 4;            // NPART divisible by 4 (COLSPLIT=8)
    float acc = 0.f;
    #pragma unroll
    for (int i = t; i < NV4; i += 64) {
        float4 v = ((const float4*)partial)[i];
        acc += (v.x + v.y) + (v.z + v.w);
    }

    #pragma unroll
    for (int off = 32; off > 0; off >>= 1)
        acc += __shfl_down(acc, off, 64);

    if (t == 0) out[0] = acc;
}

extern "C" void kernel_launch(void* const* d_in, const int* in_sizes, int n_in,
                              void* d_out, int out_size, void* d_ws, size_t ws_size,
                              hipStream_t stream) {
    const float* in  = (const float*)d_in[0];
    float* out       = (float*)d_out;
    float* partial   = (float*)d_ws;   // NPART floats (< 6 KiB)

    hinge_rows<<<NPART, THREADS, 0, stream>>>(in, partial);
    reduce_final<<<1, 64, 0, stream>>>(partial, out);
}

// Round 12
// 10.947 us; speedup vs baseline: 1.4949x; 1.1235x over previous
//
#include <hip/hip_runtime.h>

#define FEAT 2048
#define CH 8             // output rows per chunk
#define COLSPLIT 8
#define THREADS 64       // 64 threads * 4 floats = 256 = FEAT/COLSPLIT
#define NROWS_LD (CH + 4)

// total = sum_r sum_{delta=1..4} W(r,delta) * g(r, r+delta),
// g(r,s) = sum_feat relu(x_r - x_s), W(r,delta) = sum_{i=0}^{4-delta} cnt[r-i],
// cnt[v] = multiplicity of base value v = batch*distort (batch<64, distort<24).
//
// Structure note (R4-R11 measured): two plain dispatches is the FLOOR here
// (~11 us, of which ~9.5 us is fixed graph-replay/dispatch overhead).
// Single-dispatch alternatives all regress: +fill node = +10.5us, coop
// grid.sync = +46us, flat last-block counter @1456 blocks = +25us, @93
// blocks = +0.7us, hierarchical counters @372 = +5.4us. Run-to-run noise
// is ~±1us (R7 vs R11: identical kernel1, reduce_final 256->64 threads,
// "+1.35us").
struct Tables {
    int nchunk;
    short r0[1456];
    float W[1472][4];
};

constexpr Tables make_tables() {
    Tables t{};
    int cnt[1450] = {};
    for (int b = 0; b < 64; ++b)
        for (int d = 0; d < 24; ++d)
            cnt[b * d]++;
    for (int r = 0; r < 1472; ++r)
        for (int dl = 1; dl <= 4; ++dl) {
            int s = 0;
            for (int i = 0; i <= 4 - dl; ++i) {
                int v = r - i;
                if (v >= 0 && v < 1450) s += cnt[v];
            }
            t.W[r][dl - 1] = (float)s;
        }
    t.nchunk = 0;
    int r = 0;
    while (r < 1453) {
        bool act = false;
        for (int i = 0; i <= 3; ++i) {
            int v = r - i;
            if (v >= 0 && v < 1450 && cnt[v] > 0) act = true;
        }
        if (act) { t.r0[t.nchunk++] = (short)r; r += CH; }
        else ++r;
    }
    return t;
}

constexpr Tables TBL = make_tables();
constexpr int NCHUNK = TBL.nchunk;
constexpr int NPART  = NCHUNK * COLSPLIT;

__constant__ Tables d_tbl = make_tables();

__global__ __launch_bounds__(THREADS) void hinge_rows(const float* __restrict__ in,
                                                      float* __restrict__ partial) {
    const int chunk = blockIdx.x >> 3;        // / COLSPLIT
    const int cpart = blockIdx.x & 7;         // % COLSPLIT
    const int r0    = d_tbl.r0[chunk];
    const float* p  = in + (long)r0 * FEAT + cpart * (FEAT / COLSPLIT) + threadIdx.x * 4;

    // All loads upfront — independent, one latency burst.
    float4 x[NROWS_LD];
    #pragma unroll
    for (int l = 0; l < NROWS_LD; ++l)
        x[l] = *(const float4*)(p + l * FEAT);

    float acc0 = 0.f, acc1 = 0.f;
    #pragma unroll
    for (int k = 0; k < CH; ++k) {
        #pragma unroll
        for (int dl = 1; dl <= 4; ++dl) {
            const float w = d_tbl.W[r0 + k][dl - 1];
            float s = fmaxf(x[k].x - x[k + dl].x, 0.f)
                    + fmaxf(x[k].y - x[k + dl].y, 0.f)
                    + fmaxf(x[k].z - x[k + dl].z, 0.f)
                    + fmaxf(x[k].w - x[k + dl].w, 0.f);
            if (dl & 1) acc0 = fmaf(w, s, acc0);
            else        acc1 = fmaf(w, s, acc1);
        }
    }

    float acc = acc0 + acc1;
    #pragma unroll
    for (int off = 32; off > 0; off >>= 1)
        acc += __shfl_down(acc, off, 64);

    if (threadIdx.x == 0) partial[blockIdx.x] = acc;
}

__global__ __launch_bounds__(256) void reduce_final(const float* __restrict__ partial,
                                                    float* __restrict__ out) {
    const int t = threadIdx.x;
    constexpr int NV4 = NPART / 4;            // NPART divisible by 4 (COLSPLIT=8)
    float acc = 0.f;
    for (int i = t; i < NV4; i += 256) {
        float4 v = ((const float4*)partial)[i];
        acc += (v.x + v.y) + (v.z + v.w);
    }

    #pragma unroll
    for (int off = 32; off > 0; off >>= 1)
        acc += __shfl_down(acc, off, 64);

    __shared__ float ws[4];
    const int lane = t & 63, wave = t >> 6;
    if (lane == 0) ws[wave] = acc;
    __syncthreads();
    if (t == 0) out[0] = (ws[0] + ws[1]) + (ws[2] + ws[3]);
}

extern "C" void kernel_launch(void* const* d_in, const int* in_sizes, int n_in,
                              void* d_out, int out_size, void* d_ws, size_t ws_size,
                              hipStream_t stream) {
    const float* in  = (const float*)d_in[0];
    float* out       = (float*)d_out;
    float* partial   = (float*)d_ws;   // NPART floats (< 6 KiB)

    hinge_rows<<<NPART, THREADS, 0, stream>>>(in, partial);
    reduce_final<<<1, 256, 0, stream>>>(partial, out);
}